// Round 7
// baseline (101.785 us; speedup 1.0000x reference)
//
#include <hip/hip_runtime.h>
#include <hip/hip_bf16.h>
#include <stdint.h>
#include <stddef.h>

// ---------------------------------------------------------------------------
// MyConv2D fixed-point conv (Width=8), valid 3x3, NHWC, + bias + ReLU.
// R7: R6 skeleton (BM=128 BN=128 BK=64, 4 waves 2x2, A-only LDS w/ XOR
// swizzle, B global->VGPR in fragment order) plus:
//  - A prefetch depth 2: 3 LDS buffers (48 KB), stageA(t+2) in iter t.
//  - Counted waits: per iter {loadB(t+1); stageA(t+2); compute(t);
//    s_waitcnt vmcnt(4); s_barrier} -- only A(t+2) in flight across the
//    barrier; never drains to 0 until t=16 (T4 discipline).
//  - Bijective XCD-chunked block swizzle (m204): nb-pairs + mb-neighbors
//    (which share A rows) land on the same XCD's L2.
// Exactness: quantized values a/256, |a|<=256 (bf16-exact); partial sums are
// integer multiples of 2^-16 << 2^24 -> fp32 MFMA accumulation exact.
// ---------------------------------------------------------------------------

typedef float  f32x4  __attribute__((ext_vector_type(4)));
typedef short  bf16x8 __attribute__((ext_vector_type(8)));

#define N_IMG 32
#define H_IN 56
#define W_IN 56
#define C_IN 128
#define F_OUT 256
#define OHW 54
#define M_TOTAL (N_IMG * OHW * OHW)   // 93312 = 729 * 128
#define BM 128
#define BN 128
#define BK 64

__device__ __forceinline__ unsigned short quant_to_bf16(float x) {
    float a = rintf(x * 256.0f);                 // half-to-even == jnp.round
    a = fminf(fmaxf(a, -256.0f), 256.0f);
    float q = a * 0.00390625f;                   // exact in bf16
    union { float f; unsigned int u; } cv; cv.f = q;
    return (unsigned short)(cv.u >> 16);
}

__device__ __forceinline__ void async_copy16(const unsigned short* g, unsigned short* l) {
    __builtin_amdgcn_global_load_lds(
        (const __attribute__((address_space(1))) unsigned int*)g,
        (__attribute__((address_space(3))) unsigned int*)l, 16, 0, 0);
}

__global__ __launch_bounds__(256) void quant_x_kernel(
        const float* __restrict__ x, unsigned short* __restrict__ xq) {
    int i = (blockIdx.x * 256 + threadIdx.x) * 4;
    float4 v = *reinterpret_cast<const float4*>(x + i);
    ushort4 o;
    o.x = quant_to_bf16(v.x);
    o.y = quant_to_bf16(v.y);
    o.z = quant_to_bf16(v.z);
    o.w = quant_to_bf16(v.w);
    *reinterpret_cast<ushort4*>(xq + i) = o;
}

// w (3,3,128,256) -> wpf in MFMA-B fragment order:
//   idx = ((((kk*2 + hf)*2 + ks)*16 + g)*64 + l)*8 + j
//   element: f = g*16 + (l&15); c = hf*64 + ks*32 + (l>>4)*8 + j; tap kk
__global__ __launch_bounds__(256) void quant_w_kernel(
        const float* __restrict__ w, unsigned short* __restrict__ wpf) {
    int idx = blockIdx.x * 256 + threadIdx.x;     // 294912 total
    int j  = idx & 7;
    int l  = (idx >> 3) & 63;
    int g  = (idx >> 9) & 15;
    int ks = (idx >> 13) & 1;
    int hf = (idx >> 14) & 1;
    int kk = idx >> 15;
    int f  = g * 16 + (l & 15);
    int c  = hf * 64 + ks * 32 + (l >> 4) * 8 + j;
    wpf[idx] = quant_to_bf16(w[(kk * C_IN + c) * F_OUT + f]);
}

__global__ __launch_bounds__(256, 2) void conv_kernel(
        const unsigned short* __restrict__ xq,   // [32][56][56][128] bf16
        const unsigned short* __restrict__ wpf,  // fragment-ordered B
        const float* __restrict__ bias,          // [54][54][256]
        float* __restrict__ out)                 // [93312][256]
{
    __shared__ __attribute__((aligned(16))) unsigned short Alds[3][BM * BK]; // 48 KB

    const int tid  = threadIdx.x;
    const int wave = tid >> 6;
    const int lane = tid & 63;

    // bijective XCD-chunked swizzle: nwg=1458=8*182+2 (m204)
    int L;
    {
        int bid = blockIdx.x;
        int xcd = bid & 7, idx = bid >> 3;
        L = (xcd < 2) ? xcd * 183 + idx : 366 + (xcd - 2) * 182 + idx;
    }
    const int mb = L >> 1;          // consecutive L pairs share identical A
    const int nb = L & 1;
    const int m0 = mb * BM;
    const int wr = wave >> 1;       // 0..1
    const int wc = wave & 1;        // 0..1

    // ---- A staging geometry: chunk = r*256 + tid; row = (tid>>3) + 32r ----
    const int row0 = tid >> 3;                    // 0..31
    const int sw   = (tid & 7) ^ (row0 & 7);      // pre-swizzled source chunk
    const int dstc = (tid & ~63) * 8;             // wave-uniform dst (shorts)

    const unsigned short* a_base[4];
#pragma unroll
    for (int r = 0; r < 4; ++r) {
        int m = m0 + row0 + 32 * r;
        int n_img = m / (OHW * OHW);
        int rem   = m % (OHW * OHW);
        int oh = rem / OHW, ow = rem % OHW;
        a_base[r] = xq + (size_t)((n_img * H_IN + oh) * W_IN + ow) * C_IN + sw * 8;
    }

    auto stageA = [&](int t, unsigned short* Ab) {
        int kk = t >> 1, hf = t & 1;
        int kh = (kk * 43) >> 7, kw = kk - 3 * kh;   // kk/3, kk%3 for kk<=8
        int aoff = (kh * W_IN + kw) * C_IN + hf * 64;
#pragma unroll
        for (int r = 0; r < 4; ++r)
            async_copy16(a_base[r] + aoff, Ab + r * 2048 + dstc);
    };

    // ---- B fragment loads: contiguous 1 KB per wave per (ni,ks) ----
    const unsigned short* b_base = wpf + (size_t)(nb * 8 + wc * 4) * 512 + lane * 8;

    bf16x8 bregA[4][2], bregB[4][2];   // two named sets (rule #20)
    auto loadB_A = [&](int t) {
#pragma unroll
        for (int ni = 0; ni < 4; ++ni)
#pragma unroll
            for (int ks = 0; ks < 2; ++ks)
                bregA[ni][ks] = *reinterpret_cast<const bf16x8*>(
                    b_base + t * 16384 + ks * 8192 + ni * 512);
    };
    auto loadB_B = [&](int t) {
#pragma unroll
        for (int ni = 0; ni < 4; ++ni)
#pragma unroll
            for (int ks = 0; ks < 2; ++ks)
                bregB[ni][ks] = *reinterpret_cast<const bf16x8*>(
                    b_base + t * 16384 + ks * 8192 + ni * 512);
    };

    // ---- fragment read geometry (A from LDS, swizzled) ----
    const int mr = lane & 15;
    const int lq = lane >> 4;

    f32x4 acc[4][4];
#pragma unroll
    for (int i = 0; i < 4; ++i)
#pragma unroll
        for (int j = 0; j < 4; ++j) acc[i][j] = (f32x4)(0.0f);

    auto computeA = [&](const unsigned short* Ab) {   // uses bregA
#pragma unroll
        for (int ks = 0; ks < 2; ++ks) {
            const int ch = (((ks * 4 + lq) ^ (mr & 7)) * 8);
            bf16x8 af[4];
#pragma unroll
            for (int mi = 0; mi < 4; ++mi)
                af[mi] = *reinterpret_cast<const bf16x8*>(
                    Ab + (wr * 64 + mi * 16 + mr) * BK + ch);
#pragma unroll
            for (int mi = 0; mi < 4; ++mi)
#pragma unroll
                for (int ni = 0; ni < 4; ++ni)
                    acc[mi][ni] = __builtin_amdgcn_mfma_f32_16x16x32_bf16(
                        af[mi], bregA[ni][ks], acc[mi][ni], 0, 0, 0);
        }
    };
    auto computeB = [&](const unsigned short* Ab) {   // uses bregB
#pragma unroll
        for (int ks = 0; ks < 2; ++ks) {
            const int ch = (((ks * 4 + lq) ^ (mr & 7)) * 8);
            bf16x8 af[4];
#pragma unroll
            for (int mi = 0; mi < 4; ++mi)
                af[mi] = *reinterpret_cast<const bf16x8*>(
                    Ab + (wr * 64 + mi * 16 + mr) * BK + ch);
#pragma unroll
            for (int mi = 0; mi < 4; ++mi)
#pragma unroll
                for (int ni = 0; ni < 4; ++ni)
                    acc[mi][ni] = __builtin_amdgcn_mfma_f32_16x16x32_bf16(
                        af[mi], bregB[ni][ks], acc[mi][ni], 0, 0, 0);
        }
    };

    // ---- prologue: A0, B0, A1 issued; wait A0+B0 (A1 stays in flight) ----
    stageA(0, Alds[0]);
    loadB_A(0);
    stageA(1, Alds[1]);
    asm volatile("s_waitcnt vmcnt(4)" ::: "memory");
    __builtin_amdgcn_s_barrier();

    // ---- steady iters: {loadB(t+1); stageA(t+2); compute(t); vmcnt(4); bar}
#define STEP(T, CUR, NXT, LB, CP)                                   \
    LB(T + 1);                                                      \
    stageA(T + 2, Alds[NXT]);                                       \
    CP(Alds[CUR]);                                                  \
    asm volatile("s_waitcnt vmcnt(4)" ::: "memory");                \
    __builtin_amdgcn_s_barrier();

    STEP(0, 0, 2, loadB_B, computeA)
    STEP(1, 1, 0, loadB_A, computeB)
    STEP(2, 2, 1, loadB_B, computeA)
    STEP(3, 0, 2, loadB_A, computeB)
    STEP(4, 1, 0, loadB_B, computeA)
    STEP(5, 2, 1, loadB_A, computeB)
    STEP(6, 0, 2, loadB_B, computeA)
    STEP(7, 1, 0, loadB_A, computeB)
    STEP(8, 2, 1, loadB_B, computeA)
    STEP(9, 0, 2, loadB_A, computeB)
    STEP(10, 1, 0, loadB_B, computeA)
    STEP(11, 2, 1, loadB_A, computeB)
    STEP(12, 0, 2, loadB_B, computeA)
    STEP(13, 1, 0, loadB_A, computeB)
    STEP(14, 2, 1, loadB_B, computeA)
    STEP(15, 0, 2, loadB_A, computeB)
#undef STEP

    // t=16: load B(17); compute(16) from buf 1; full drain (once, near end)
    loadB_B(17);
    computeA(Alds[1]);
    asm volatile("s_waitcnt vmcnt(0)" ::: "memory");
    __builtin_amdgcn_s_barrier();
    // t=17: last tile
    computeB(Alds[2]);

    // ---- epilogue: quantize, bias, ReLU ----
    const int fcol0 = nb * BN + wc * 64 + mr;
#pragma unroll
    for (int mi = 0; mi < 4; ++mi) {
#pragma unroll
        for (int rr = 0; rr < 4; ++rr) {
            const int m = m0 + wr * 64 + mi * 16 + lq * 4 + rr;
            const float* brow = bias + (size_t)(m % (OHW * OHW)) * F_OUT;
            float* orow = out + (size_t)m * F_OUT;
#pragma unroll
            for (int ni = 0; ni < 4; ++ni) {
                float v = acc[mi][ni][rr];
                float t = rintf(v * 256.0f);
                t = fminf(fmaxf(t, -256.0f), 256.0f);
                float o = t * 0.00390625f + brow[fcol0 + ni * 16];
                orow[fcol0 + ni * 16] = fmaxf(o, 0.0f);
            }
        }
    }
}

extern "C" void kernel_launch(void* const* d_in, const int* in_sizes, int n_in,
                              void* d_out, int out_size, void* d_ws, size_t ws_size,
                              hipStream_t stream) {
    (void)in_sizes; (void)n_in; (void)out_size;
    const float* x    = (const float*)d_in[0];
    const float* w    = (const float*)d_in[1];
    const float* bias = (const float*)d_in[2];
    float* out        = (float*)d_out;

    const size_t x_elems = (size_t)N_IMG * H_IN * W_IN * C_IN;
    const size_t w_elems = (size_t)9 * F_OUT * C_IN;
    const size_t xq_bytes = x_elems * sizeof(unsigned short);  // 16B-aligned
    const size_t need = xq_bytes + w_elems * sizeof(unsigned short);
    if (ws_size < need) return;

    unsigned short* xq  = (unsigned short*)d_ws;
    unsigned short* wpf = (unsigned short*)((char*)d_ws + xq_bytes);

    quant_x_kernel<<<(int)(x_elems / (256 * 4)), 256, 0, stream>>>(x, xq);
    quant_w_kernel<<<(int)(w_elems / 256), 256, 0, stream>>>(w, wpf);
    conv_kernel<<<(M_TOTAL / BM) * 2, 256, 0, stream>>>(xq, wpf, bias, out);
}